// Round 12
// baseline (311.559 us; speedup 1.0000x reference)
//
#include <hip/hip_runtime.h>

// NeRF fused render, R12: masked-affine + crossing-bitmask correction.
// R11's exact identity, but the rare correction path is a DATA-DEPENDENT
// while-loop over a 64-bit crossing mask -- the compiler cannot if-convert
// a runtime-trip loop, so the ~3500-op flattened body (R11's failure) becomes
// 64x16 branch-free ops + ~3 iterations of a 56-op correction body.
//   loop1 (unrolled): P_c += w_c*A*mask0, Q_c += w_c*B*mask0; cmask bit per h
//                     iff relu crossing falls inside this lane's 8-sample chunk
//   loop2 (while cmask): ck = max(s*g_k,0), s = act0?-1:+1; acc_c += ck*w_c
//   per sample: c_c = b2_c + fma(m, Q_c, P_c) + acc_c[k]; composite as R4.

typedef float v2f __attribute__((ext_vector_type(2)));
typedef float v4f __attribute__((ext_vector_type(4)));

constexpr int S_TOTAL = 128;
constexpr int TPR     = 16;            // lanes per ray
constexpr int SPT     = S_TOTAL / TPR; // 8 samples per lane
constexpr int BLOCK   = 256;
constexpr int RPB     = BLOCK / TPR;   // 16 rays per block
constexpr int H       = 64;

__global__ __launch_bounds__(BLOCK, 6)
void nerf_cross(const float* __restrict__ origins,
                const float* __restrict__ directions,
                const float* __restrict__ nearp,
                const float* __restrict__ farp,
                const float* __restrict__ W1,   // [3][64]
                const float* __restrict__ b1,   // [64]
                const float* __restrict__ W2,   // [64][4]
                const float* __restrict__ b2,   // [4]
                float* __restrict__ out,        // [B][3]
                int B)
{
    // ABs2[r][h] = {A,B}; ray stride 520B -> 4 per-wave bcast addrs distinct banks
    __shared__ v2f ABs2[RPB][H + 1];
    __shared__ v4f W2q[H];               // {w0,w1,w2,w3} per h
    __shared__ float b2s[4];

    const int tid  = threadIdx.x;
    const int ray0 = blockIdx.x * RPB;

    if (tid < H) W2q[tid] = *reinterpret_cast<const v4f*>(&W2[tid * 4]);
    if (tid < 4) b2s[tid] = b2[tid];

#pragma unroll
    for (int idx = tid; idx < RPB * H; idx += BLOCK) {
        const int r   = idx >> 6;        // / H
        const int h   = idx & (H - 1);
        const int ray = ray0 + r;
        const float o0 = origins[ray * 3 + 0];
        const float o1 = origins[ray * 3 + 1];
        const float o2 = origins[ray * 3 + 2];
        float d0 = directions[ray * 3 + 0];
        float d1 = directions[ray * 3 + 1];
        float d2 = directions[ray * 3 + 2];
        const float nrm  = sqrtf(d0 * d0 + d1 * d1 + d2 * d2);
        const float rinv = 1.0f / fmaxf(nrm, 1e-12f);
        d0 *= rinv; d1 *= rinv; d2 *= rinv;
        const float u0 = W1[0 * H + h];
        const float u1 = W1[1 * H + h];
        const float u2 = W1[2 * H + h];
        const float A  = fmaf(o2, u2, fmaf(o1, u1, fmaf(o0, u0, b1[h])));
        const float Bc = fmaf(d2, u2, fmaf(d1, u1, d0 * u0));
        ABs2[r][h] = (v2f){A, Bc};
    }
    __syncthreads();

    const int sub  = tid & (TPR - 1);    // lane within ray group
    const int rloc = tid >> 4;           // local ray index
    const int ray  = ray0 + rloc;

    const float nr    = nearp[0];
    const float fr    = farp[0];
    const float delta = (fr - nr) * (1.0f / (float)S_TOTAL);

    // this lane's 8 sample midpoints
    float m[SPT];
    m[0] = fmaf((float)(sub * SPT) + 0.5f, delta, nr);
#pragma unroll
    for (int k = 1; k < SPT; ++k) m[k] = m[k - 1] + delta;
    const float m0 = m[0], m7 = m[SPT - 1];

    // per-(channel,sample) corrections, seeded with b2
    float acc[4][SPT];
#pragma unroll
    for (int k = 0; k < SPT; ++k) {
        acc[0][k] = b2s[0]; acc[1][k] = b2s[1];
        acc[2][k] = b2s[2]; acc[3][k] = b2s[3];
    }

    float P0 = 0.f, P1 = 0.f, P2 = 0.f, P3 = 0.f;
    float Q0 = 0.f, Q1 = 0.f, Q2 = 0.f, Q3 = 0.f;
    unsigned long long cmask = 0ull;

    // ---- loop 1: branch-free masked-affine accumulation + crossing mask ----
#pragma unroll
    for (int h = 0; h < H; ++h) {
        const v2f ab = ABs2[rloc][h];    // {A,B} broadcast per 16-lane group
        const v4f w  = W2q[h];           // wave-uniform broadcast
        const float g0 = fmaf(m0, ab.y, ab.x);
        const float g7 = fmaf(m7, ab.y, ab.x);
        const bool act0 = g0 > 0.0f;
        const bool act7 = g7 > 0.0f;
        const float Am = act0 ? ab.x : 0.0f;
        const float Bm = act0 ? ab.y : 0.0f;
        P0 = fmaf(w.x, Am, P0); P1 = fmaf(w.y, Am, P1);
        P2 = fmaf(w.z, Am, P2); P3 = fmaf(w.w, Am, P3);
        Q0 = fmaf(w.x, Bm, Q0); Q1 = fmaf(w.y, Bm, Q1);
        Q2 = fmaf(w.z, Bm, Q2); Q3 = fmaf(w.w, Bm, Q3);
        cmask |= ((unsigned long long)(act0 != act7)) << h;  // h is constant
    }

    // ---- loop 2: data-dependent correction loop (cannot be if-converted) ----
    while (cmask) {
        const int h = __builtin_ctzll(cmask);
        cmask &= cmask - 1ull;
        const v2f ab = ABs2[rloc][h];
        const v4f w  = W2q[h];
        const float g0 = fmaf(m0, ab.y, ab.x);
        const float s  = (g0 > 0.0f) ? -1.0f : 1.0f;
        const float sA = s * ab.x;
        const float sB = s * ab.y;
#pragma unroll
        for (int k = 0; k < SPT; ++k) {
            const float ck = fmaxf(fmaf(m[k], sB, sA), 0.0f); // relu corr
            acc[0][k] = fmaf(ck, w.x, acc[0][k]);
            acc[1][k] = fmaf(ck, w.y, acc[1][k]);
            acc[2][k] = fmaf(ck, w.z, acc[2][k]);
            acc[3][k] = fmaf(ck, w.w, acc[3][k]);
        }
    }

    // ---- composite over this lane's 8 samples (verified R4 form) ----
    float Tloc = 1.0f, orr = 0.0f, og = 0.0f, ob = 0.0f;
#pragma unroll
    for (int k = 0; k < SPT; ++k) {
        const float c0 = fmaf(m[k], Q0, P0) + acc[0][k];
        const float c1 = fmaf(m[k], Q1, P1) + acc[1][k];
        const float c2 = fmaf(m[k], Q2, P2) + acc[2][k];
        const float sg = fmaf(m[k], Q3, P3) + acc[3][k];
        const float sig = __expf(sg);
        const float e   = __expf(-sig * delta);  // = 1 - alpha
        Tloc *= e;                               // inclusive cumprod
        const float w = Tloc * (1.0f - e);       // T * alpha
        orr = fmaf(w, __expf(c0), orr);
        og  = fmaf(w, __expf(c1), og);
        ob  = fmaf(w, __expf(c2), ob);
    }

    // ---- stitch across the 16 lanes of this ray (verified R4 form) ----
    float scan = Tloc;
#pragma unroll
    for (int off = 1; off < TPR; off <<= 1) {
        const float v = __shfl_up(scan, off, TPR);
        if (sub >= off) scan *= v;
    }
    float pre = __shfl_up(scan, 1, TPR);
    if (sub == 0) pre = 1.0f;

    orr *= pre; og *= pre; ob *= pre;
#pragma unroll
    for (int off = TPR / 2; off > 0; off >>= 1) {
        orr += __shfl_down(orr, off, TPR);
        og  += __shfl_down(og,  off, TPR);
        ob  += __shfl_down(ob,  off, TPR);
    }

    if (sub == 0) {
        out[ray * 3 + 0] = orr;
        out[ray * 3 + 1] = og;
        out[ray * 3 + 2] = ob;
    }
}

extern "C" void kernel_launch(void* const* d_in, const int* in_sizes, int n_in,
                              void* d_out, int out_size, void* d_ws, size_t ws_size,
                              hipStream_t stream) {
    const float* origins    = (const float*)d_in[0];
    const float* directions = (const float*)d_in[1];
    const float* nearp      = (const float*)d_in[2];
    const float* farp       = (const float*)d_in[3];
    const float* W1         = (const float*)d_in[4];
    const float* b1         = (const float*)d_in[5];
    const float* W2         = (const float*)d_in[6];
    const float* b2         = (const float*)d_in[7];
    float* out              = (float*)d_out;

    const int B     = in_sizes[0] / 3;       // 32768
    const int total = B * TPR;
    const int grid  = (total + BLOCK - 1) / BLOCK;

    nerf_cross<<<grid, BLOCK, 0, stream>>>(origins, directions, nearp, farp,
                                           W1, b1, W2, b2, out, B);
}